// Round 3
// baseline (657.631 us; speedup 1.0000x reference)
//
#include <hip/hip_runtime.h>
#include <hip/hip_cooperative_groups.h>
#include <math.h>

namespace cg = cooperative_groups;

#define W 1024
#define H 768
#define PIX (W*H)          // 786432
#define NIMG 4
#define SNUM 131072
#define GRID 1024          // 256 blocks/image, 4 blocks/CU -> all co-resident
#define BPI 256            // blocks per image
#define PPB 3072           // pixels per block (3 full rows)
#define PPT 12             // pixels per thread (consecutive, for stable compaction)
#define SPB 512            // loss samples per block (2 per thread)
#define MASKV (-1e-8f)

// {input, target} packed per pixel: one cache line per random pixel access
__device__ __forceinline__ void pair_acc2(const float2* __restrict__ pIT,
                                          int A, int B, float& eqs, float& uns) {
    float2 a = pIT[A], b = pIT[B];
    float cm = ((a.y > MASKV) ? 1.f : 0.f) * ((b.y > MASKV) ? 1.f : 0.f);
    float ratio = (a.y + 1e-6f) / (b.y + 1e-6f);
    const float HIv = 1.03f;
    const float LOv = (float)(1.0 / 1.03);
    bool eq = (ratio < HIv) && (ratio > LOv);
    if (eq) {
        float d = a.x - b.x;
        eqs += d * d * cm;
    } else {
        float label = ((ratio >= HIv) ? 1.f : 0.f) + ((ratio <= LOv) ? -1.f : 0.f);
        uns += log1pf(expf((b.x - a.x) * label)) * cm;
    }
}

__global__ __launch_bounds__(256, 4) void fused_kernel(
    const float* __restrict__ inputs, const float* __restrict__ targets,
    const float* __restrict__ images,
    const int* __restrict__ ra, const int* __restrict__ rd, const int* __restrict__ rp,
    float2* __restrict__ pairIT, float2* __restrict__ anchorC, int* __restrict__ compV,
    float* __restrict__ blockmax, int* __restrict__ blkV, int* __restrict__ blkE,
    float2* __restrict__ partials, float* __restrict__ out)
{
    cg::grid_group grid = cg::this_grid();
    const int b = blockIdx.x, t = threadIdx.x;
    const int i = b >> 8, bLoc = b & 255;
    const int pixBase = bLoc * PPB;               // first pixel (in-image) of this block
    const size_t imgOff = (size_t)i * PIX;

    __shared__ float sE[PPB];                     // edge magnitude, persists across phases
    __shared__ float sTh[PPB];                    // theta, persists
    __shared__ unsigned sEm[98], sVm[98];         // 3072-bit masks (+2 zero pad words)
    __shared__ int sExcE[256], sExcV[256];        // per-thread exclusive offsets
    __shared__ int sScan[256];
    __shared__ float sFScan[256];
    __shared__ float sRq[256], sRu[256];
    __shared__ double sDr[256];
    __shared__ int sMeta[3];                      // [0]=vOffBlk [1]=vTot [2]=eTot
    __shared__ float sThr;

    // ================= P1: Sobel + theta + pack {inp,tgt} + valid bits =================
    if (t < 2) { sVm[96 + t] = 0; sEm[96 + t] = 0; }
    float bmax = 0.f;
    const float* img = images + (size_t)i * 3 * PIX;   // channel 0
    for (int k = 0; k < PPT; k++) {
        int p = k * 256 + t;                      // strided -> coalesced global access
        int gp = pixBase + p;
        int y = gp >> 10, x = gp & (W - 1);
        float e = 0.f, th = 0.f;
        if (y >= 1 && y <= H - 2 && x >= 1 && x <= W - 2) {
            const float* r0 = img + (y - 1) * W + x;
            const float* r1 = r0 + W;
            const float* r2 = r1 + W;
            float a00 = r0[-1], a01 = r0[0], a02 = r0[1];
            float a10 = r1[-1],              a12 = r1[1];
            float a20 = r2[-1], a21 = r2[0], a22 = r2[1];
            float gx = (a02 - a00) + 2.f * (a12 - a10) + (a22 - a20);
            float gy = (a00 - a20) + 2.f * (a01 - a21) + (a02 - a22);
            e = sqrtf(gx * gx + gy * gy);
            th = atan2f(gy, gx);
        }
        sE[p] = e; sTh[p] = th;
        bmax = fmaxf(bmax, e);
        float inv = inputs[imgOff + gp];
        float tgv = targets[imgOff + gp];
        pairIT[imgOff + gp] = make_float2(inv, tgv);
        unsigned long long m = __ballot(tgv > MASKV);
        if ((t & 63) == 0)  sVm[k * 8 + (t >> 5)] = (unsigned)m;
        if ((t & 63) == 32) sVm[k * 8 + (t >> 5)] = (unsigned)(m >> 32);
    }
    sFScan[t] = bmax;
    __syncthreads();                              // also publishes sVm, sE, sTh
    for (int off = 128; off > 0; off >>= 1) {
        if (t < off) sFScan[t] = fmaxf(sFScan[t], sFScan[t + off]);
        __syncthreads();
    }
    if (t == 0) blockmax[b] = sFScan[0];
    {   // stable valid-count scan over consecutive 12-pixel windows
        int start = t * PPT, w = start >> 5, sh = start & 31;
        unsigned long long win = (((unsigned long long)sVm[w + 1] << 32) | sVm[w]) >> sh;
        int cV = __popcll(win & 0xFFFull);
        sScan[t] = cV;
        __syncthreads();
        for (int off = 1; off < 256; off <<= 1) {
            int v = (t >= off) ? sScan[t - off] : 0;
            __syncthreads();
            sScan[t] += v;
            __syncthreads();
        }
        sExcV[t] = sScan[t] - cV;
        if (t == 255) blkV[b] = sScan[255];
    }
    grid.sync();   // ---- S1 ----

    // ================= P2: per-block redundant emax + blkV prefix; edge bits =================
    sFScan[t] = blockmax[i * BPI + t];
    __syncthreads();
    for (int off = 128; off > 0; off >>= 1) {
        if (t < off) sFScan[t] = fmaxf(sFScan[t], sFScan[t + off]);
        __syncthreads();
    }
    if (t == 0) sThr = 0.1f * sFScan[0];
    sScan[t] = blkV[i * BPI + t];
    __syncthreads();
    for (int off = 1; off < 256; off <<= 1) {
        int v = (t >= off) ? sScan[t - off] : 0;
        __syncthreads();
        sScan[t] += v;
        __syncthreads();
    }
    if (t == 0) {
        sMeta[0] = (bLoc > 0) ? sScan[bLoc - 1] : 0;   // this block's valid write offset
        sMeta[1] = sScan[255];                          // vtot for this image
    }
    __syncthreads();
    {   // edge bits (strided ballots against thr), then stable edge-count scan
        float thr = sThr;
        for (int k = 0; k < PPT; k++) {
            int p = k * 256 + t;
            unsigned long long m = __ballot(sE[p] >= thr);
            if ((t & 63) == 0)  sEm[k * 8 + (t >> 5)] = (unsigned)m;
            if ((t & 63) == 32) sEm[k * 8 + (t >> 5)] = (unsigned)(m >> 32);
        }
        __syncthreads();
        int start = t * PPT, w = start >> 5, sh = start & 31;
        unsigned long long win = (((unsigned long long)sEm[w + 1] << 32) | sEm[w]) >> sh;
        int cE = __popcll(win & 0xFFFull);
        sScan[t] = cE;
        __syncthreads();
        for (int off = 1; off < 256; off <<= 1) {
            int v = (t >= off) ? sScan[t - off] : 0;
            __syncthreads();
            sScan[t] += v;
            __syncthreads();
        }
        sExcE[t] = sScan[t] - cE;
        if (t == 255) blkE[b] = sScan[255];
    }
    grid.sync();   // ---- S2 ----

    // ================= P3: blkE prefix + scatter {pix,theta} / compV =================
    sScan[t] = blkE[i * BPI + t];
    __syncthreads();
    for (int off = 1; off < 256; off <<= 1) {
        int v = (t >= off) ? sScan[t - off] : 0;
        __syncthreads();
        sScan[t] += v;
        __syncthreads();
    }
    if (t == 0) sMeta[2] = sScan[255];            // etot for this image
    __syncthreads();
    {
        int eo = ((bLoc > 0) ? sScan[bLoc - 1] : 0) + sExcE[t];
        int vo = sMeta[0] + sExcV[t];
        int vTot = sMeta[1];
        int start = t * PPT, w = start >> 5, sh = start & 31;
        unsigned long long winE = (((unsigned long long)sEm[w + 1] << 32) | sEm[w]) >> sh;
        unsigned long long winV = (((unsigned long long)sVm[w + 1] << 32) | sVm[w]) >> sh;
        bool writeV = (vTot < PIX);               // all-valid => compV[r]==r, skip entirely
        for (int j = 0; j < PPT; j++) {
            int p = start + j, gp = pixBase + p;
            if ((winE >> j) & 1) anchorC[imgOff + (eo++)] = make_float2(__int_as_float(gp), sTh[p]);
            if (writeV && ((winV >> j) & 1)) compV[imgOff + (vo++)] = gp;
        }
    }
    grid.sync();   // ---- S3 ----

    // ================= P4: loss (2 samples/thread) =================
    {
        int eTot = sMeta[2], vTot = sMeta[1];
        int minlen = (eTot > 0) ? eTot : 1;       // eTot>=1 always (thr<=emax)
        int nval = (vTot > 0) ? vTot : 1;
        const float2* pIT = pairIT + imgOff;
        float eqs = 0.f, uns = 0.f;
        for (int k = 0; k < 2; k++) {
            int s = bLoc * SPB + k * 256 + t;
            int j = ra[(size_t)i * SNUM + s] % minlen;
            float2 ac = anchorC[imgOff + j];      // 8B gather in compact region
            int anchor = __float_as_int(ac.x);
            float th = ac.y;
            float sv = sinf(th), cv = cosf(th);
            int row_a = anchor >> 10, col_a = anchor & (W - 1);
            int pix4[4];
#pragma unroll
            for (int kk = 0; kk < 4; kk++) {
                int r = rd[((size_t)i * 4 + kk) * SNUM + s];
                float dist = ((float)r + 2.0f) * ((kk < 2) ? -1.f : 1.f);
                int cc = col_a + (int)rintf(dist * cv);
                int rr = row_a + (int)rintf(dist * sv);
                cc = min(max(cc, 0), W - 1);
                rr = min(max(rr, 0), H - 1);
                pix4[kk] = (rr << 10) | cc;
            }
            pair_acc2(pIT, pix4[0], pix4[1], eqs, uns);
            pair_acc2(pIT, pix4[1], pix4[2], eqs, uns);
            pair_acc2(pIT, pix4[2], pix4[3], eqs, uns);
            int2 rr2 = *(const int2*)(rp + (size_t)i * 2 * SNUM + 2 * s);
            int r0 = rr2.x % nval, r1 = rr2.y % nval;
            bool ident = (vTot == PIX) || (vTot == 0);   // identity mapping cases
            int A = ident ? r0 : compV[imgOff + r0];
            int B = ident ? r1 : compV[imgOff + r1];
            pair_acc2(pIT, A, B, eqs, uns);
        }
        sRq[t] = eqs; sRu[t] = uns;
        __syncthreads();
        for (int off = 128; off > 0; off >>= 1) {
            if (t < off) { sRq[t] += sRq[t + off]; sRu[t] += sRu[t + off]; }
            __syncthreads();
        }
        if (t == 0) partials[b] = make_float2(sRq[0], sRu[0]);
    }
    grid.sync();   // ---- S4 ----

    // ================= P5: final reduce (block 0 only) =================
    if (b == 0) {
        float2 p0 = partials[t], p1 = partials[t + 256];
        float2 p2 = partials[t + 512], p3 = partials[t + 768];
        double s = (double)p0.x + (double)p0.y + (double)p1.x + (double)p1.y
                 + (double)p2.x + (double)p2.y + (double)p3.x + (double)p3.y;
        sDr[t] = s;
        __syncthreads();
        for (int off = 128; off > 0; off >>= 1) {
            if (t < off) sDr[t] += sDr[t + off];
            __syncthreads();
        }
        if (t == 0) {
            double denom = 4.0 * (double)SNUM;    // each mean over 4*S pair terms; ALPHA=1
            out[0] = (float)(sDr[0] / denom / (double)NIMG);
        }
    }
}

extern "C" void kernel_launch(void* const* d_in, const int* in_sizes, int n_in,
                              void* d_out, int out_size, void* d_ws, size_t ws_size,
                              hipStream_t stream) {
    const float* inputs  = (const float*)d_in[0];
    const float* targets = (const float*)d_in[1];
    const float* images  = (const float*)d_in[2];
    const int* ra = (const int*)d_in[3];
    const int* rd = (const int*)d_in[4];
    const int* rp = (const int*)d_in[5];
    float* out = (float*)d_out;

    char* ws = (char*)d_ws;
    float*  blockmax = (float*)ws;                       // [1024]
    int*    blkV     = (int*)(ws + 4096);                // [1024]
    int*    blkE     = (int*)(ws + 8192);                // [1024]
    float2* partials = (float2*)(ws + 12288);            // [1024] float2 = 8KB
    float2* pairIT   = (float2*)(ws + 32768);            // NIMG*PIX float2 = 25.2MB
    float2* anchorC  = pairIT + (size_t)NIMG * PIX;      // 25.2MB (worst case)
    int*    compV    = (int*)(anchorC + (size_t)NIMG * PIX);  // 12.6MB
    // total ~62.9MB; every word written before read (compV read only when written)

    void* args[] = {(void*)&inputs, (void*)&targets, (void*)&images,
                    (void*)&ra, (void*)&rd, (void*)&rp,
                    (void*)&pairIT, (void*)&anchorC, (void*)&compV,
                    (void*)&blockmax, (void*)&blkV, (void*)&blkE,
                    (void*)&partials, (void*)&out};
    hipLaunchCooperativeKernel(reinterpret_cast<void*>(fused_kernel),
                               dim3(GRID), dim3(256), args, 0, stream);
}

// Round 4
// 190.356 us; speedup vs baseline: 3.4547x; 3.4547x over previous
//
#include <hip/hip_runtime.h>
#include <math.h>

#define W 1024
#define H 768
#define PIX (W*H)          // 786432
#define NIMG 4
#define SNUM 131072
#define BPI 3072           // blocks per image, 256 pixels each
#define NB (NIMG*BPI)      // 12288
#define MASKV (-1e-8f)

__device__ __forceinline__ void sobel_g(const float* __restrict__ img, int y, int x,
                                        float& gx, float& gy) {
    const float* r0 = img + (y - 1) * W + x;
    const float* r1 = r0 + W;
    const float* r2 = r1 + W;
    float a00 = r0[-1], a01 = r0[0], a02 = r0[1];
    float a10 = r1[-1],              a12 = r1[1];
    float a20 = r2[-1], a21 = r2[0], a22 = r2[1];
    gx = (a02 - a00) + 2.f * (a12 - a10) + (a22 - a20);
    gy = (a00 - a20) + 2.f * (a01 - a21) + (a02 - a22);
}

// ---- K0: Sobel magnitude + block max + pack {inp,tgt} + valid bits/counts ----
__global__ void sobel_pack_kernel(const float* __restrict__ inputs,
                                  const float* __restrict__ targets,
                                  const float* __restrict__ images,
                                  float2* __restrict__ pairIT,
                                  unsigned long long* __restrict__ vBits,
                                  float* __restrict__ blockmax,
                                  int* __restrict__ blkV) {
    int b = blockIdx.x, t = threadIdx.x;
    int i = b / BPI, bLoc = b - i * BPI;
    int gp = bLoc * 256 + t;
    int y = gp >> 10, x = gp & (W - 1);
    const float* img = images + (size_t)i * 3 * PIX;   // channel 0
    float e = 0.f;
    if (y >= 1 && y <= H - 2 && x >= 1 && x <= W - 2) {
        float gx, gy;
        sobel_g(img, y, x, gx, gy);
        e = sqrtf(gx * gx + gy * gy);
    }
    size_t off = (size_t)i * PIX + gp;
    float inv = inputs[off], tgv = targets[off];
    pairIT[off] = make_float2(inv, tgv);
    unsigned long long m = __ballot(tgv > MASKV);
    __shared__ float sm[256];
    __shared__ int sc[4];
    if ((t & 63) == 0) { vBits[off >> 6] = m; sc[t >> 6] = __popcll(m); }
    sm[t] = e;
    __syncthreads();
    for (int o = 128; o > 0; o >>= 1) {
        if (t < o) sm[t] = fmaxf(sm[t], sm[t + o]);
        __syncthreads();
    }
    if (t == 0) { blockmax[b] = sm[0]; blkV[b] = sc[0] + sc[1] + sc[2] + sc[3]; }
}

// ---- K1: per-image emax->thr + exclusive scan of blkV (3072 entries) ----
__global__ void emax_scanv_kernel(const float* __restrict__ blockmax,
                                  int* __restrict__ blkV,
                                  float* __restrict__ thrArr, int* __restrict__ vtot) {
    int i = blockIdx.x, t = threadIdx.x;   // 1024 threads
    __shared__ float sf[1024];
    __shared__ int si[1024];
    const float* bm = blockmax + i * BPI;
    sf[t] = fmaxf(fmaxf(bm[t], bm[t + 1024]), bm[t + 2048]);
    int* bv = blkV + i * BPI;
    int e0 = bv[3 * t], e1 = bv[3 * t + 1], e2 = bv[3 * t + 2];
    int s = e0 + e1 + e2;
    si[t] = s;
    __syncthreads();
    for (int o = 512; o > 0; o >>= 1) {
        if (t < o) sf[t] = fmaxf(sf[t], sf[t + o]);
        __syncthreads();
    }
    for (int o = 1; o < 1024; o <<= 1) {
        int v = (t >= o) ? si[t - o] : 0;
        __syncthreads();
        si[t] += v;
        __syncthreads();
    }
    int base = si[t] - s;
    bv[3 * t] = base; bv[3 * t + 1] = base + e0; bv[3 * t + 2] = base + e0 + e1;
    if (t == 0) thrArr[i] = 0.1f * sf[0];
    if (t == 1023) vtot[i] = si[1023];
}

// ---- K2: edge bits + per-block edge counts (Sobel recomputed) ----
__global__ void ebits_kernel(const float* __restrict__ images,
                             const float* __restrict__ thrArr,
                             unsigned long long* __restrict__ eBits,
                             int* __restrict__ blkE) {
    int b = blockIdx.x, t = threadIdx.x;
    int i = b / BPI, bLoc = b - i * BPI;
    int gp = bLoc * 256 + t;
    int y = gp >> 10, x = gp & (W - 1);
    const float* img = images + (size_t)i * 3 * PIX;
    float e = 0.f;
    if (y >= 1 && y <= H - 2 && x >= 1 && x <= W - 2) {
        float gx, gy;
        sobel_g(img, y, x, gx, gy);
        e = sqrtf(gx * gx + gy * gy);
    }
    float thr = thrArr[i];
    unsigned long long m = __ballot(e >= thr);
    __shared__ int sc[4];
    if ((t & 63) == 0) { eBits[((size_t)i * PIX + gp) >> 6] = m; sc[t >> 6] = __popcll(m); }
    __syncthreads();
    if (t == 0) blkE[b] = sc[0] + sc[1] + sc[2] + sc[3];
}

// ---- K3: exclusive scan of blkE ----
__global__ void scane_kernel(int* __restrict__ blkE, int* __restrict__ etot) {
    int i = blockIdx.x, t = threadIdx.x;
    __shared__ int si[1024];
    int* be = blkE + i * BPI;
    int e0 = be[3 * t], e1 = be[3 * t + 1], e2 = be[3 * t + 2];
    int s = e0 + e1 + e2;
    si[t] = s;
    __syncthreads();
    for (int o = 1; o < 1024; o <<= 1) {
        int v = (t >= o) ? si[t - o] : 0;
        __syncthreads();
        si[t] += v;
        __syncthreads();
    }
    int base = si[t] - s;
    be[3 * t] = base; be[3 * t + 1] = base + e0; be[3 * t + 2] = base + e0 + e1;
    if (t == 1023) etot[i] = si[1023];
}

// ---- K4: scatter {pixel,theta} for edge pixels; compV only if not all-valid ----
__global__ void scatter_kernel(const float* __restrict__ images,
                               const unsigned long long* __restrict__ eBits,
                               const unsigned long long* __restrict__ vBits,
                               const int* __restrict__ blkE, const int* __restrict__ blkV,
                               const int* __restrict__ vtot,
                               float2* __restrict__ anchorC, int* __restrict__ compV) {
    int b = blockIdx.x, t = threadIdx.x;
    int i = b / BPI, bLoc = b - i * BPI;
    int gp = bLoc * 256 + t;
    int lane = t & 63, w = t >> 6;
    size_t woff = ((size_t)i * PIX + bLoc * 256) >> 6;
    unsigned long long em = eBits[woff + w], vm = vBits[woff + w];
    __shared__ int sWE[4], sWV[4];
    if (lane == 0) { sWE[w] = __popcll(em); sWV[w] = __popcll(vm); }
    __syncthreads();
    int preE = 0, preV = 0;
    for (int k = 0; k < w; k++) { preE += sWE[k]; preV += sWV[k]; }
    unsigned long long lm = (1ull << lane) - 1ull;
    int erank = blkE[b] + preE + __popcll(em & lm);
    int vrank = blkV[b] + preV + __popcll(vm & lm);
    if ((em >> lane) & 1) {
        int y = gp >> 10, x = gp & (W - 1);
        float th = 0.f;
        if (y >= 1 && y <= H - 2 && x >= 1 && x <= W - 2) {
            float gx, gy;
            const float* img = images + (size_t)i * 3 * PIX;
            sobel_g(img, y, x, gx, gy);
            th = atan2f(gy, gx);
        }
        anchorC[(size_t)i * PIX + erank] = make_float2(__int_as_float(gp), th);
    }
    if (((vm >> lane) & 1) && vtot[i] < PIX) compV[(size_t)i * PIX + vrank] = gp;
}

// ---- loss ----
__device__ __forceinline__ void pair_term(float2 a, float2 b, float& eqs, float& uns) {
    float cm = ((a.y > MASKV) ? 1.f : 0.f) * ((b.y > MASKV) ? 1.f : 0.f);
    float ratio = (a.y + 1e-6f) / (b.y + 1e-6f);
    const float HIv = 1.03f;
    const float LOv = (float)(1.0 / 1.03);
    bool eq = (ratio < HIv) && (ratio > LOv);
    if (eq) {
        float d = a.x - b.x;
        eqs += d * d * cm;
    } else {
        float label = ((ratio >= HIv) ? 1.f : 0.f) + ((ratio <= LOv) ? -1.f : 0.f);
        uns += log1pf(expf((b.x - a.x) * label)) * cm;
    }
}

__global__ void loss_kernel(const float2* __restrict__ pairIT,
                            const float2* __restrict__ anchorC,
                            const int* __restrict__ compV,
                            const int* __restrict__ etot, const int* __restrict__ vtot,
                            const int* __restrict__ ra, const int* __restrict__ rd,
                            const int* __restrict__ rp,
                            float2* __restrict__ partials) {
    int i = blockIdx.y;
    int s = blockIdx.x * 256 + threadIdx.x;
    const float2* pIT = pairIT + (size_t)i * PIX;
    int eT = etot[i], vT = vtot[i];
    int minlen = (eT > 0) ? eT : 1;
    int nval = (vT > 0) ? vT : 1;

    int j = ra[(size_t)i * SNUM + s] % minlen;
    float2 ac = anchorC[(size_t)i * PIX + j];      // one 8B line: pixel + theta
    int anchor = __float_as_int(ac.x);
    float sv = sinf(ac.y), cv = cosf(ac.y);
    int row_a = anchor >> 10, col_a = anchor & (W - 1);

    int pix4[4];
#pragma unroll
    for (int k = 0; k < 4; k++) {
        int r = rd[((size_t)i * 4 + k) * SNUM + s];
        float dist = ((float)r + 2.0f) * ((k < 2) ? -1.f : 1.f);
        int cc = col_a + (int)rintf(dist * cv);    // round-half-even = jnp.round
        int rr = row_a + (int)rintf(dist * sv);
        cc = min(max(cc, 0), W - 1);
        rr = min(max(rr, 0), H - 1);
        pix4[k] = (rr << 10) | cc;
    }
    int2 rr2 = *(const int2*)(rp + (size_t)i * 2 * SNUM + 2 * s);
    int r0 = rr2.x % nval, r1 = rr2.y % nval;
    bool ident = (vT == PIX) || (vT == 0);         // identity compaction cases
    int A = ident ? r0 : compV[(size_t)i * PIX + r0];
    int B = ident ? r1 : compV[(size_t)i * PIX + r1];

    float2 a0 = pIT[pix4[0]], a1 = pIT[pix4[1]], a2 = pIT[pix4[2]], a3 = pIT[pix4[3]];
    float2 b0 = pIT[A], b1 = pIT[B];
    float eqs = 0.f, uns = 0.f;
    pair_term(a0, a1, eqs, uns);
    pair_term(a1, a2, eqs, uns);
    pair_term(a2, a3, eqs, uns);
    pair_term(b0, b1, eqs, uns);

    __shared__ float sEq[256], sUn[256];
    sEq[threadIdx.x] = eqs; sUn[threadIdx.x] = uns;
    __syncthreads();
    for (int o = 128; o > 0; o >>= 1) {
        if (threadIdx.x < o) {
            sEq[threadIdx.x] += sEq[threadIdx.x + o];
            sUn[threadIdx.x] += sUn[threadIdx.x + o];
        }
        __syncthreads();
    }
    if (threadIdx.x == 0)
        partials[i * 512 + blockIdx.x] = make_float2(sEq[0], sUn[0]);
}

__global__ void final_kernel(const float2* __restrict__ partials, float* __restrict__ out) {
    int t = threadIdx.x;                           // 1024 threads, 2048 partials
    float2 a = partials[t], b = partials[t + 1024];
    double s = (double)a.x + (double)a.y + (double)b.x + (double)b.y;
    __shared__ double sm[1024];
    sm[t] = s;
    __syncthreads();
    for (int o = 512; o > 0; o >>= 1) {
        if (t < o) sm[t] += sm[t + o];
        __syncthreads();
    }
    if (t == 0) {
        double denom = 4.0 * (double)SNUM;
        out[0] = (float)(sm[0] / denom / (double)NIMG);   // ALPHA = 1
    }
}

extern "C" void kernel_launch(void* const* d_in, const int* in_sizes, int n_in,
                              void* d_out, int out_size, void* d_ws, size_t ws_size,
                              hipStream_t stream) {
    const float* inputs  = (const float*)d_in[0];
    const float* targets = (const float*)d_in[1];
    const float* images  = (const float*)d_in[2];
    const int* ra = (const int*)d_in[3];
    const int* rd = (const int*)d_in[4];
    const int* rp = (const int*)d_in[5];
    float* out = (float*)d_out;

    char* ws = (char*)d_ws;
    float*  thrArr   = (float*)ws;                         // [4]
    int*    etot     = (int*)(ws + 16);                    // [4]
    int*    vtot     = (int*)(ws + 32);                    // [4]
    float*  blockmax = (float*)(ws + 64);                  // [12288]
    int*    blkE     = (int*)(ws + 49216);                 // [12288]
    int*    blkV     = (int*)(ws + 98368);                 // [12288]
    float2* partials = (float2*)(ws + 147520);             // [2048]
    unsigned long long* vBits = (unsigned long long*)(ws + 196608);   // 393216 B
    unsigned long long* eBits = (unsigned long long*)(ws + 589824);   // 393216 B
    float2* pairIT   = (float2*)(ws + 1048576);            // 25.2 MB
    float2* anchorC  = (float2*)(ws + 26214400);           // 25.2 MB (worst case)
    int*    compV    = (int*)(ws + 51380224);              // 12.6 MB
    // total ~61 MB; every word written before read -> no memset needed

    sobel_pack_kernel<<<NB, 256, 0, stream>>>(inputs, targets, images,
                                              pairIT, vBits, blockmax, blkV);
    emax_scanv_kernel<<<NIMG, 1024, 0, stream>>>(blockmax, blkV, thrArr, vtot);
    ebits_kernel<<<NB, 256, 0, stream>>>(images, thrArr, eBits, blkE);
    scane_kernel<<<NIMG, 1024, 0, stream>>>(blkE, etot);
    scatter_kernel<<<NB, 256, 0, stream>>>(images, eBits, vBits, blkE, blkV, vtot,
                                           anchorC, compV);
    loss_kernel<<<dim3(SNUM / 256, NIMG), 256, 0, stream>>>(pairIT, anchorC, compV,
                                                            etot, vtot, ra, rd, rp, partials);
    final_kernel<<<1, 1024, 0, stream>>>(partials, out);
}